// Round 1
// baseline (496.713 us; speedup 1.0000x reference)
//
#include <hip/hip_runtime.h>

#define NN 50000
#define NE 600000
#define DD 128
#define XS 264   // padded LDS row stride in bf16 elems: 528 B = 33*16 (16B aligned), %32-dword offset 4 -> 2-way bank alias (free)

typedef unsigned short u16;
typedef u16   u16x8  __attribute__((ext_vector_type(8)));
typedef u16   u16x4  __attribute__((ext_vector_type(4)));
typedef __bf16 bf16x8 __attribute__((ext_vector_type(8)));
typedef float f32x4  __attribute__((ext_vector_type(4)));

__device__ __forceinline__ u16 f2bf(float f) {  // RNE fp32->bf16
    unsigned u = __builtin_bit_cast(unsigned, f);
    u += 0x7FFFu + ((u >> 16) & 1u);
    return (u16)(u >> 16);
}

// node_features fp32 [NN,DD] -> bf16 table
__global__ void k_convert_nf(const float* __restrict__ nf, u16* __restrict__ out) {
    int id = blockIdx.x * 256 + threadIdx.x;            // NN*DD/4 threads exactly
    float4 v = ((const float4*)nf)[id];
    u16x4 o; o[0] = f2bf(v.x); o[1] = f2bf(v.y); o[2] = f2bf(v.z); o[3] = f2bf(v.w);
    ((u16x4*)out)[id] = o;
}

// Pack W[K,N] fp32 row-major into MFMA B-fragment order for 16x16x32:
// frag = nt*KT + kt (KT = K/32); within frag: lane*8 + j holds
// W[kt*32 + (lane>>4)*8 + j][nt*16 + (lane&15)]
__global__ void k_pack(const float* __restrict__ W, u16* __restrict__ out, int K, int N) {
    int tid = blockIdx.x * 256 + threadIdx.x;
    if (tid >= K * N) return;
    int frag = tid >> 9, lane = (tid >> 3) & 63, j = tid & 7;
    int KT = K >> 5;
    int nt = frag / KT, kt = frag - nt * KT;
    int row = kt * 32 + ((lane >> 4) << 3) + j;
    int col = nt * 16 + (lane & 15);
    out[tid] = f2bf(W[row * N + col]);
}

// Edge kernel: 64 edges/block, 128 threads (2 waves), each wave owns 32 rows (2 m-tiles).
// X = [from_feat | to_feat] (64 x 256 bf16) in LDS; H reuses same buffer (rows wave-private).
__global__ __launch_bounds__(128) void k_edges(
    const u16* __restrict__ nf16, const int* __restrict__ from_idx,
    const int* __restrict__ to_idx, const u16* __restrict__ pW0,
    const float* __restrict__ b0, const u16* __restrict__ pW1,
    const float* __restrict__ b1, float* __restrict__ agg)
{
    __shared__ u16 sX[64 * XS];
    const int tid = threadIdx.x;
    const int e0 = blockIdx.x * 64;

    // stage gather: 64 rows x 32 chunks of 8 bf16 (16 B)
    #pragma unroll
    for (int i = 0; i < 16; ++i) {
        int c = i * 128 + tid;
        int r = c >> 5, j = c & 31;
        int e = e0 + r;
        int node = (j < 16) ? from_idx[e] : to_idx[e];
        *(u16x8*)(&sX[r * XS + j * 8]) = *(const u16x8*)(nf16 + node * DD + (j & 15) * 8);
    }
    __syncthreads();

    const int lane = tid & 63;
    const int wave = tid >> 6;
    const int base = wave * 32;
    const int l15  = lane & 15;
    const int quad = lane >> 4;
    const int arow0 = (base + l15) * XS + quad * 8;

    // consume X fully into registers (A-frags), freeing sX rows for H
    bf16x8 a[2][8];
    #pragma unroll
    for (int mt = 0; mt < 2; ++mt)
        #pragma unroll
        for (int kt = 0; kt < 8; ++kt)
            a[mt][kt] = __builtin_bit_cast(bf16x8, *(const u16x8*)(&sX[arow0 + mt * 16 * XS + kt * 32]));

    // layer 0: H[64,256] = relu(X @ W0 + b0)
    for (int nt = 0; nt < 16; ++nt) {
        f32x4 c0 = {0.f, 0.f, 0.f, 0.f}, c1 = {0.f, 0.f, 0.f, 0.f};
        #pragma unroll
        for (int kt = 0; kt < 8; ++kt) {
            bf16x8 b = __builtin_bit_cast(bf16x8, *(const u16x8*)(pW0 + (nt * 8 + kt) * 512 + lane * 8));
            c0 = __builtin_amdgcn_mfma_f32_16x16x32_bf16(a[0][kt], b, c0, 0, 0, 0);
            c1 = __builtin_amdgcn_mfma_f32_16x16x32_bf16(a[1][kt], b, c1, 0, 0, 0);
        }
        float bias = b0[nt * 16 + l15];
        #pragma unroll
        for (int i = 0; i < 4; ++i) {
            sX[(base +      quad * 4 + i) * XS + nt * 16 + l15] = f2bf(fmaxf(c0[i] + bias, 0.f));
            sX[(base + 16 + quad * 4 + i) * XS + nt * 16 + l15] = f2bf(fmaxf(c1[i] + bias, 0.f));
        }
    }

    // layer 1 A-frags from H (same rows, in-wave ordered: no barrier needed)
    #pragma unroll
    for (int mt = 0; mt < 2; ++mt)
        #pragma unroll
        for (int kt = 0; kt < 8; ++kt)
            a[mt][kt] = __builtin_bit_cast(bf16x8, *(const u16x8*)(&sX[arow0 + mt * 16 * XS + kt * 32]));

    int tI[2][4];
    #pragma unroll
    for (int mt = 0; mt < 2; ++mt)
        #pragma unroll
        for (int i = 0; i < 4; ++i)
            tI[mt][i] = to_idx[e0 + base + mt * 16 + quad * 4 + i];

    // layer 1: m = relu(H @ W1 + b1), scatter-add into agg
    for (int nt = 0; nt < 8; ++nt) {
        f32x4 c0 = {0.f, 0.f, 0.f, 0.f}, c1 = {0.f, 0.f, 0.f, 0.f};
        #pragma unroll
        for (int kt = 0; kt < 8; ++kt) {
            bf16x8 b = __builtin_bit_cast(bf16x8, *(const u16x8*)(pW1 + (nt * 8 + kt) * 512 + lane * 8));
            c0 = __builtin_amdgcn_mfma_f32_16x16x32_bf16(a[0][kt], b, c0, 0, 0, 0);
            c1 = __builtin_amdgcn_mfma_f32_16x16x32_bf16(a[1][kt], b, c1, 0, 0, 0);
        }
        float bias = b1[nt * 16 + l15];
        int col = nt * 16 + l15;
        #pragma unroll
        for (int i = 0; i < 4; ++i) {
            unsafeAtomicAdd(&agg[(size_t)tI[0][i] * DD + col], fmaxf(c0[i] + bias, 0.f));
            unsafeAtomicAdd(&agg[(size_t)tI[1][i] * DD + col], fmaxf(c1[i] + bias, 0.f));
        }
    }
}

// Node update: out = nf + relu(relu([agg|nf] @ uW0 + ub0) @ uW1 + ub1)
__global__ __launch_bounds__(128) void k_update(
    const float* __restrict__ agg, const u16* __restrict__ nf16,
    const float* __restrict__ nf32, const u16* __restrict__ pW0,
    const float* __restrict__ b0, const u16* __restrict__ pW1,
    const float* __restrict__ b1, float* __restrict__ out)
{
    __shared__ u16 sX[64 * XS];
    const int tid = threadIdx.x;
    const int n0 = blockIdx.x * 64;

    // stage agg half (cols 0..127), fp32->bf16
    #pragma unroll
    for (int i = 0; i < 16; ++i) {
        int c = i * 128 + tid;
        int r = c >> 5, j = c & 31;
        int n = n0 + r;
        u16x4 o;
        if (n < NN) {
            float4 v = *(const float4*)(agg + (size_t)n * DD + j * 4);
            o[0] = f2bf(v.x); o[1] = f2bf(v.y); o[2] = f2bf(v.z); o[3] = f2bf(v.w);
        } else { o[0] = 0; o[1] = 0; o[2] = 0; o[3] = 0; }
        *(u16x4*)(&sX[r * XS + j * 4]) = o;
    }
    // stage nf half (cols 128..255), bf16 copy
    #pragma unroll
    for (int i = 0; i < 8; ++i) {
        int c = i * 128 + tid;
        int r = c >> 4, j = c & 15;
        int n = n0 + r;
        u16x8 v = {0, 0, 0, 0, 0, 0, 0, 0};
        if (n < NN) v = *(const u16x8*)(nf16 + (size_t)n * DD + j * 8);
        *(u16x8*)(&sX[r * XS + 128 + j * 8]) = v;
    }
    __syncthreads();

    const int lane = tid & 63;
    const int wave = tid >> 6;
    const int base = wave * 32;
    const int l15  = lane & 15;
    const int quad = lane >> 4;
    const int arow0 = (base + l15) * XS + quad * 8;

    bf16x8 a[2][8];
    #pragma unroll
    for (int mt = 0; mt < 2; ++mt)
        #pragma unroll
        for (int kt = 0; kt < 8; ++kt)
            a[mt][kt] = __builtin_bit_cast(bf16x8, *(const u16x8*)(&sX[arow0 + mt * 16 * XS + kt * 32]));

    for (int nt = 0; nt < 16; ++nt) {
        f32x4 c0 = {0.f, 0.f, 0.f, 0.f}, c1 = {0.f, 0.f, 0.f, 0.f};
        #pragma unroll
        for (int kt = 0; kt < 8; ++kt) {
            bf16x8 b = __builtin_bit_cast(bf16x8, *(const u16x8*)(pW0 + (nt * 8 + kt) * 512 + lane * 8));
            c0 = __builtin_amdgcn_mfma_f32_16x16x32_bf16(a[0][kt], b, c0, 0, 0, 0);
            c1 = __builtin_amdgcn_mfma_f32_16x16x32_bf16(a[1][kt], b, c1, 0, 0, 0);
        }
        float bias = b0[nt * 16 + l15];
        #pragma unroll
        for (int i = 0; i < 4; ++i) {
            sX[(base +      quad * 4 + i) * XS + nt * 16 + l15] = f2bf(fmaxf(c0[i] + bias, 0.f));
            sX[(base + 16 + quad * 4 + i) * XS + nt * 16 + l15] = f2bf(fmaxf(c1[i] + bias, 0.f));
        }
    }

    #pragma unroll
    for (int mt = 0; mt < 2; ++mt)
        #pragma unroll
        for (int kt = 0; kt < 8; ++kt)
            a[mt][kt] = __builtin_bit_cast(bf16x8, *(const u16x8*)(&sX[arow0 + mt * 16 * XS + kt * 32]));

    for (int nt = 0; nt < 8; ++nt) {
        f32x4 c0 = {0.f, 0.f, 0.f, 0.f}, c1 = {0.f, 0.f, 0.f, 0.f};
        #pragma unroll
        for (int kt = 0; kt < 8; ++kt) {
            bf16x8 b = __builtin_bit_cast(bf16x8, *(const u16x8*)(pW1 + (nt * 8 + kt) * 512 + lane * 8));
            c0 = __builtin_amdgcn_mfma_f32_16x16x32_bf16(a[0][kt], b, c0, 0, 0, 0);
            c1 = __builtin_amdgcn_mfma_f32_16x16x32_bf16(a[1][kt], b, c1, 0, 0, 0);
        }
        float bias = b1[nt * 16 + l15];
        int col = nt * 16 + l15;
        #pragma unroll
        for (int i = 0; i < 4; ++i) {
            int na = n0 + base +      quad * 4 + i;
            int nb = n0 + base + 16 + quad * 4 + i;
            if (na < NN) out[(size_t)na * DD + col] = nf32[(size_t)na * DD + col] + fmaxf(c0[i] + bias, 0.f);
            if (nb < NN) out[(size_t)nb * DD + col] = nf32[(size_t)nb * DD + col] + fmaxf(c1[i] + bias, 0.f);
        }
    }
}

extern "C" void kernel_launch(void* const* d_in, const int* in_sizes, int n_in,
                              void* d_out, int out_size, void* d_ws, size_t ws_size,
                              hipStream_t stream)
{
    const float* nf  = (const float*)d_in[0];
    const int* fidx  = (const int*)d_in[1];
    const int* tidx  = (const int*)d_in[2];
    const float* mW0 = (const float*)d_in[3];
    const float* mb0 = (const float*)d_in[4];
    const float* mW1 = (const float*)d_in[5];
    const float* mb1 = (const float*)d_in[6];
    const float* uW0 = (const float*)d_in[7];
    const float* ub0 = (const float*)d_in[8];
    const float* uW1 = (const float*)d_in[9];
    const float* ub1 = (const float*)d_in[10];
    float* out = (float*)d_out;

    char* ws = (char*)d_ws;
    u16*   nf16 = (u16*)ws;   ws += (size_t)NN * DD * 2;   // 12.8 MB
    float* agg  = (float*)ws; ws += (size_t)NN * DD * 4;   // 25.6 MB
    u16*   pmW0 = (u16*)ws;   ws += 256 * 256 * 2;
    u16*   pmW1 = (u16*)ws;   ws += 256 * 128 * 2;
    u16*   puW0 = (u16*)ws;   ws += 256 * 256 * 2;
    u16*   puW1 = (u16*)ws;   ws += 256 * 128 * 2;

    hipMemsetAsync(agg, 0, (size_t)NN * DD * 4, stream);
    k_convert_nf<<<(NN * DD / 4) / 256, 256, 0, stream>>>(nf, nf16);
    k_pack<<<256, 256, 0, stream>>>(mW0, pmW0, 256, 256);
    k_pack<<<128, 256, 0, stream>>>(mW1, pmW1, 256, 128);
    k_pack<<<256, 256, 0, stream>>>(uW0, puW0, 256, 256);
    k_pack<<<128, 256, 0, stream>>>(uW1, puW1, 256, 128);
    k_edges<<<NE / 64, 128, 0, stream>>>(nf16, fidx, tidx, pmW0, mb0, pmW1, mb1, agg);
    k_update<<<(NN + 63) / 64, 128, 0, stream>>>(agg, nf16, nf, puW0, ub0, puW1, ub1, out);
}